// Round 14
// baseline (911.229 us; speedup 1.0000x reference)
//
#include <hip/hip_runtime.h>
#include <hip/hip_cooperative_groups.h>

namespace cg = cooperative_groups;

// GCN: 3 layers, dims 64->64->64->32, N=100000 nodes, E=1600000 edges.
// Round 14 (= R13 + occupancy-clamped cooperative launch): ONE mega-kernel,
// grid.sync() between phases. R13 failed because hardcoded G=1024 exceeded the
// runtime's max cooperative grid (launch error returned synchronously, out
// never written -- absmax identical to the round-0 stub). Now G comes from
// hipOccupancyMaxActiveBlocksPerMultiprocessor (deterministic, capture-safe),
// with halving retries as belt-and-braces.
// R10/R11 evidence: ~115us of the 299us total was dispatch boundaries.
// fp16 inter-layer storage, fp32 accumulation, zero global atomics.

typedef __attribute__((ext_vector_type(8))) _Float16 half8;

__host__ __device__ static inline int cdiv(int a, int b) { return (a + b - 1) / b; }

#define MAXNBK 512   // max buckets (N <= 131072); NBK = cdiv(N,256)

__global__ __launch_bounds__(256, 4)
void gcn_mega(const float* __restrict__ x, const int* __restrict__ src,
              const int* __restrict__ dst,
              const float* __restrict__ W1, const float* __restrict__ b1,
              const float* __restrict__ W2, const float* __restrict__ b2,
              const float* __restrict__ W3, const float* __restrict__ b3,
              float* __restrict__ out,
              int* counts_t, int* offsets, int* bsum, int* row_start, float* dis,
              unsigned* bucketed, int* csr_src,
              _Float16* bufA, _Float16* bufB,
              int N, int E, int NBK) {
    cg::grid_group grid = cg::this_grid();
    const int G = gridDim.x;
    const int t = threadIdx.x;
    const int b = blockIdx.x;

    __shared__ union {
        struct { int cnt[MAXNBK]; } hist;              // 2KB
        struct { int red[256]; } scan;                 // 1KB
        struct { int curs[MAXNBK]; } scat;             // 2KB
        struct { int cnt[256]; int sc[256]; } build;   // 2KB
        struct { float Ws[64 * 64]; float Xs[32 * 65]; } gemm;  // 24.3KB
    } u;

    // ================= phase 1: per-block bucket histogram =================
    {
        for (int i = t; i < NBK; i += 256) u.hist.cnt[i] = 0;
        __syncthreads();
        int chb = cdiv(E, G);
        int e0 = b * chb, e1 = min(E, e0 + chb);
        for (int e = e0 + t; e < e1; e += 256)
            atomicAdd(&u.hist.cnt[dst[e] >> 8], 1);
        __syncthreads();
        for (int i = t; i < NBK; i += 256) counts_t[i * G + b] = u.hist.cnt[i];
    }
    grid.sync();

    // ================= phase 2: exclusive scan of counts_t[0..NBK*G) =======
    const int ch = NBK;  // elems per block; NBK <= 512 -> <= 2/thread
    {   // 2a: per-block partial sums -> bsum[b]
        int i0 = b * ch, i1 = i0 + ch;
        int s = 0;
        for (int j = 0; j < 2; ++j) {
            int i = i0 + t * 2 + j;
            if (i < i1) s += counts_t[i];
        }
        u.scan.red[t] = s;
        __syncthreads();
        for (int off = 128; off > 0; off >>= 1) {
            if (t < off) u.scan.red[t] += u.scan.red[t + off];
            __syncthreads();
        }
        if (t == 0) bsum[b] = u.scan.red[0];
    }
    grid.sync();
    {   // 2b: block 0 scans bsum[0..G) exclusive (G <= 1024, 4/thread)
        if (b == 0) {
            int v[4];
            int s = 0;
            for (int j = 0; j < 4; ++j) {
                int i = t * 4 + j;
                v[j] = (i < G) ? bsum[i] : 0;
                s += v[j];
            }
            u.scan.red[t] = s;
            __syncthreads();
            for (int off = 1; off < 256; off <<= 1) {
                int uu = (t >= off) ? u.scan.red[t - off] : 0;
                __syncthreads();
                u.scan.red[t] += uu;
                __syncthreads();
            }
            int run = u.scan.red[t] - s;
            for (int j = 0; j < 4; ++j) {
                int i = t * 4 + j;
                if (i < G) { bsum[i] = run; run += v[j]; }
            }
        }
    }
    grid.sync();
    {   // 2c: per-block final scan -> offsets
        int i0 = b * ch, i1 = i0 + ch;
        int v[2];
        int s = 0;
        for (int j = 0; j < 2; ++j) {
            int i = i0 + t * 2 + j;
            v[j] = (i < i1) ? counts_t[i] : 0;
            s += v[j];
        }
        u.scan.red[t] = s;
        __syncthreads();
        for (int off = 1; off < 256; off <<= 1) {
            int uu = (t >= off) ? u.scan.red[t - off] : 0;
            __syncthreads();
            u.scan.red[t] += uu;
            __syncthreads();
        }
        int run = u.scan.red[t] - s + bsum[b];
        for (int j = 0; j < 2; ++j) {
            int i = i0 + t * 2 + j;
            if (i < i1) { offsets[i] = run; run += v[j]; }
        }
    }
    grid.sync();

    // ================= phase 3: scatter into bucket regions ================
    {
        for (int i = t; i < NBK; i += 256) u.scat.curs[i] = offsets[i * G + b];
        __syncthreads();
        int chb = cdiv(E, G);
        int e0 = b * chb, e1 = min(E, e0 + chb);
        for (int e = e0 + t; e < e1; e += 256) {
            int d = dst[e];
            int pos = atomicAdd(&u.scat.curs[d >> 8], 1);
            bucketed[pos] = (unsigned)src[e] | ((unsigned)(d & 255) << 24);
        }
    }
    grid.sync();

    // ================= phase 4: per-bucket build (csr_src,row_start,dis) ===
    for (int k = b; k < NBK; k += G) {
        int base = offsets[k * G];
        int end = (k + 1 < NBK) ? offsets[(k + 1) * G] : E;
        u.build.cnt[t] = 0;
        __syncthreads();
        for (int i = base + t; i < end; i += 256)
            atomicAdd(&u.build.cnt[bucketed[i] >> 24], 1);
        __syncthreads();
        int c = u.build.cnt[t];
        u.build.sc[t] = c;
        __syncthreads();
        for (int off = 1; off < 256; off <<= 1) {
            int uu = (t >= off) ? u.build.sc[t - off] : 0;
            __syncthreads();
            u.build.sc[t] += uu;
            __syncthreads();
        }
        int excl = u.build.sc[t] - c;
        int node = k * 256 + t;
        if (node < N) {
            row_start[node] = base + excl;
            dis[node] = rsqrtf(1.0f + (float)c);
        }
        if (k == 0 && t == 0) row_start[N] = E;
        u.build.cnt[t] = base + excl;  // cursor
        __syncthreads();
        for (int i = base + t; i < end; i += 256) {
            unsigned v = bucketed[i];
            int pos = atomicAdd(&u.build.cnt[v >> 24], 1);
            csr_src[pos] = (int)(v & 0xFFFFFFu);
        }
        __syncthreads();
    }
    grid.sync();

    // ================= phase 5: gemm1  x(fp32) @ W1 -> bufA (fp16) =========
    {
        for (int idx = t; idx < 64 * 64 / 4; idx += 256)
            ((float4*)u.gemm.Ws)[idx] = ((const float4*)W1)[idx];
        int tiles = cdiv(N, 32);
        int r = t / 8, c0 = (t % 8) * 8;
        for (int tb = b; tb < tiles; tb += G) {
            int row0 = tb * 32;
            __syncthreads();
            for (int idx = t; idx < 32 * 16; idx += 256) {
                int rr = idx / 16, kq = idx % 16;
                int row = row0 + rr;
                float4 vv = (row < N) ? ((const float4*)x)[(size_t)row * 16 + kq]
                                      : make_float4(0.f, 0.f, 0.f, 0.f);
                float* xp = &u.gemm.Xs[rr * 65 + kq * 4];
                xp[0] = vv.x; xp[1] = vv.y; xp[2] = vv.z; xp[3] = vv.w;
            }
            __syncthreads();
            int row = row0 + r;
            if (row < N) {
                float4 a0 = make_float4(0.f, 0.f, 0.f, 0.f);
                float4 a1 = make_float4(0.f, 0.f, 0.f, 0.f);
#pragma unroll
                for (int k = 0; k < 64; ++k) {
                    float xv = u.gemm.Xs[r * 65 + k];
                    float4 w0 = ((const float4*)u.gemm.Ws)[(k * 64 + c0) / 4];
                    float4 w1 = ((const float4*)u.gemm.Ws)[(k * 64 + c0) / 4 + 1];
                    a0.x = fmaf(xv, w0.x, a0.x);
                    a0.y = fmaf(xv, w0.y, a0.y);
                    a0.z = fmaf(xv, w0.z, a0.z);
                    a0.w = fmaf(xv, w0.w, a0.w);
                    a1.x = fmaf(xv, w1.x, a1.x);
                    a1.y = fmaf(xv, w1.y, a1.y);
                    a1.z = fmaf(xv, w1.z, a1.z);
                    a1.w = fmaf(xv, w1.w, a1.w);
                }
                float dn = dis[row];
                half8 hv;
                hv[0] = (_Float16)(a0.x * dn);
                hv[1] = (_Float16)(a0.y * dn);
                hv[2] = (_Float16)(a0.z * dn);
                hv[3] = (_Float16)(a0.w * dn);
                hv[4] = (_Float16)(a1.x * dn);
                hv[5] = (_Float16)(a1.y * dn);
                hv[6] = (_Float16)(a1.z * dn);
                hv[7] = (_Float16)(a1.w * dn);
                ((half8*)bufA)[(size_t)row * 8 + c0 / 8] = hv;
            }
        }
    }
    grid.sync();

    // ===== phases 6,7: fused aggregate(64)+relu -> LDS -> GEMM -> fp16 =====
#define FUSED_PHASE(MOUT, HSRC, BAGG, WMAT, HDST)                                 \
    {                                                                             \
        for (int idx = t; idx < 64 * MOUT / 4; idx += 256)                        \
            ((float4*)u.gemm.Ws)[idx] = ((const float4*)WMAT)[idx];               \
        int tiles = cdiv(N, 32);                                                  \
        int wave = t >> 6, lane = t & 63, sub = lane >> 3, fl = lane & 7;         \
        const int TPR = MOUT / 8;                                                 \
        int r = t / TPR, c0 = (t % TPR) * 8;                                      \
        const half8* h8 = (const half8*)HSRC;                                     \
        for (int tb = b; tb < tiles; tb += G) {                                   \
            int node0 = tb * 32;                                                  \
            __syncthreads();                                                      \
            int node = node0 + wave * 8 + sub;                                    \
            if (node < N) {                                                       \
                float acc[8];                                                     \
                _Pragma("unroll") for (int j = 0; j < 8; ++j) acc[j] = 0.f;       \
                int e = row_start[node], e1 = row_start[node + 1];                \
                for (; e + 3 < e1; e += 4) {                                      \
                    int s0 = csr_src[e], s1 = csr_src[e + 1];                     \
                    int s2 = csr_src[e + 2], s3 = csr_src[e + 3];                 \
                    half8 v0 = h8[(size_t)s0 * 8 + fl];                           \
                    half8 v1 = h8[(size_t)s1 * 8 + fl];                           \
                    half8 v2 = h8[(size_t)s2 * 8 + fl];                           \
                    half8 v3 = h8[(size_t)s3 * 8 + fl];                           \
                    _Pragma("unroll") for (int j = 0; j < 8; ++j)                 \
                        acc[j] += ((float)v0[j] + (float)v1[j]) +                 \
                                  ((float)v2[j] + (float)v3[j]);                  \
                }                                                                 \
                for (; e < e1; ++e) {                                             \
                    int s0 = csr_src[e];                                          \
                    half8 v0 = h8[(size_t)s0 * 8 + fl];                           \
                    _Pragma("unroll") for (int j = 0; j < 8; ++j)                 \
                        acc[j] += (float)v0[j];                                   \
                }                                                                 \
                float dn = dis[node];                                             \
                half8 hv = h8[(size_t)node * 8 + fl];                             \
                float4 bb0 = ((const float4*)BAGG)[fl * 2];                       \
                float4 bb1 = ((const float4*)BAGG)[fl * 2 + 1];                   \
                float* xp = &u.gemm.Xs[(wave * 8 + sub) * 65 + fl * 8];           \
                xp[0] = fmaxf((acc[0] + (float)hv[0]) * dn + bb0.x, 0.f);         \
                xp[1] = fmaxf((acc[1] + (float)hv[1]) * dn + bb0.y, 0.f);         \
                xp[2] = fmaxf((acc[2] + (float)hv[2]) * dn + bb0.z, 0.f);         \
                xp[3] = fmaxf((acc[3] + (float)hv[3]) * dn + bb0.w, 0.f);         \
                xp[4] = fmaxf((acc[4] + (float)hv[4]) * dn + bb1.x, 0.f);         \
                xp[5] = fmaxf((acc[5] + (float)hv[5]) * dn + bb1.y, 0.f);         \
                xp[6] = fmaxf((acc[6] + (float)hv[6]) * dn + bb1.z, 0.f);         \
                xp[7] = fmaxf((acc[7] + (float)hv[7]) * dn + bb1.w, 0.f);         \
            }                                                                     \
            __syncthreads();                                                      \
            int row = node0 + r;                                                  \
            if (r < 32 && row < N) {                                              \
                float4 a0 = make_float4(0.f, 0.f, 0.f, 0.f);                      \
                float4 a1 = make_float4(0.f, 0.f, 0.f, 0.f);                      \
                _Pragma("unroll") for (int k = 0; k < 64; ++k) {                  \
                    float xv = u.gemm.Xs[r * 65 + k];                             \
                    float4 w0 = ((const float4*)u.gemm.Ws)[(k * MOUT + c0) / 4];  \
                    float4 w1 = ((const float4*)u.gemm.Ws)[(k * MOUT + c0) / 4 + 1];\
                    a0.x = fmaf(xv, w0.x, a0.x);                                  \
                    a0.y = fmaf(xv, w0.y, a0.y);                                  \
                    a0.z = fmaf(xv, w0.z, a0.z);                                  \
                    a0.w = fmaf(xv, w0.w, a0.w);                                  \
                    a1.x = fmaf(xv, w1.x, a1.x);                                  \
                    a1.y = fmaf(xv, w1.y, a1.y);                                  \
                    a1.z = fmaf(xv, w1.z, a1.z);                                  \
                    a1.w = fmaf(xv, w1.w, a1.w);                                  \
                }                                                                 \
                float dn = dis[row];                                              \
                half8 hv;                                                         \
                hv[0] = (_Float16)(a0.x * dn);                                    \
                hv[1] = (_Float16)(a0.y * dn);                                    \
                hv[2] = (_Float16)(a0.z * dn);                                    \
                hv[3] = (_Float16)(a0.w * dn);                                    \
                hv[4] = (_Float16)(a1.x * dn);                                    \
                hv[5] = (_Float16)(a1.y * dn);                                    \
                hv[6] = (_Float16)(a1.z * dn);                                    \
                hv[7] = (_Float16)(a1.w * dn);                                    \
                ((half8*)HDST)[(size_t)row * (MOUT / 8) + c0 / 8] = hv;           \
            }                                                                     \
        }                                                                         \
    }

    FUSED_PHASE(64, bufA, b1, W2, bufB)
    grid.sync();
    FUSED_PHASE(32, bufB, b2, W3, bufA)
    grid.sync();

    // ================= phase 8: final aggregate(32) -> out (fp32) ==========
    {
        int lane = t & 63, sub = lane >> 2, fl = lane & 3;  // LPN=4, NPW=16
        int nw = cdiv(N, 16);
        const half8* h8 = (const half8*)bufA;
        for (int wv = b * 4 + (t >> 6); wv < nw; wv += G * 4) {
            int node = wv * 16 + sub;
            if (node >= N) continue;
            float acc[8];
#pragma unroll
            for (int j = 0; j < 8; ++j) acc[j] = 0.f;
            int e = row_start[node], e1 = row_start[node + 1];
            for (; e + 3 < e1; e += 4) {
                int s0 = csr_src[e], s1 = csr_src[e + 1];
                int s2 = csr_src[e + 2], s3 = csr_src[e + 3];
                half8 v0 = h8[(size_t)s0 * 4 + fl];
                half8 v1 = h8[(size_t)s1 * 4 + fl];
                half8 v2 = h8[(size_t)s2 * 4 + fl];
                half8 v3 = h8[(size_t)s3 * 4 + fl];
#pragma unroll
                for (int j = 0; j < 8; ++j)
                    acc[j] += ((float)v0[j] + (float)v1[j]) + ((float)v2[j] + (float)v3[j]);
            }
            for (; e < e1; ++e) {
                int s0 = csr_src[e];
                half8 v0 = h8[(size_t)s0 * 4 + fl];
#pragma unroll
                for (int j = 0; j < 8; ++j) acc[j] += (float)v0[j];
            }
            float dn = dis[node];
            half8 hv = h8[(size_t)node * 4 + fl];
            float4 bb0 = ((const float4*)b3)[fl * 2];
            float4 bb1 = ((const float4*)b3)[fl * 2 + 1];
            float4* op = (float4*)(out + ((size_t)node * 4 + fl) * 8);
            op[0] = make_float4((acc[0] + (float)hv[0]) * dn + bb0.x,
                                (acc[1] + (float)hv[1]) * dn + bb0.y,
                                (acc[2] + (float)hv[2]) * dn + bb0.z,
                                (acc[3] + (float)hv[3]) * dn + bb0.w);
            op[1] = make_float4((acc[4] + (float)hv[4]) * dn + bb1.x,
                                (acc[5] + (float)hv[5]) * dn + bb1.y,
                                (acc[6] + (float)hv[6]) * dn + bb1.z,
                                (acc[7] + (float)hv[7]) * dn + bb1.w);
        }
    }
}

extern "C" void kernel_launch(void* const* d_in, const int* in_sizes, int n_in,
                              void* d_out, int out_size, void* d_ws, size_t ws_size,
                              hipStream_t stream) {
    const float* x  = (const float*)d_in[0];
    const int*   ei = (const int*)d_in[1];
    const float* W1 = (const float*)d_in[2];
    const float* b1 = (const float*)d_in[3];
    const float* W2 = (const float*)d_in[4];
    const float* b2 = (const float*)d_in[5];
    const float* W3 = (const float*)d_in[6];
    const float* b3 = (const float*)d_in[7];
    float* out = (float*)d_out;

    int N = in_sizes[0] / 64;
    int E = in_sizes[1] / 2;
    const int* src = ei;
    const int* dst = ei + E;
    int NBK = cdiv(N, 256);

    // Determine max cooperative grid (deterministic, capture-safe host query).
    int maxB = 0;
    hipError_t qerr = hipOccupancyMaxActiveBlocksPerMultiprocessor(&maxB, gcn_mega, 256, 0);
    if (qerr != hipSuccess || maxB < 1) maxB = 1;
    int G = maxB * 256;          // 256 CUs on MI355X
    if (G > 1024) G = 1024;      // kernel scan supports G <= 1024
    if (G < 128) G = 128;

    // workspace layout (sized for G_max = 1024; kernel uses gridDim.x <= that)
    const size_t Np = (size_t)((N + 63) / 64) * 64;
    const size_t nmat_max = (size_t)NBK * 1024;
    char* p = (char*)d_ws;
    int*      counts_t = (int*)p;      p += nmat_max * sizeof(int);
    int*      offsets  = (int*)p;      p += nmat_max * sizeof(int);
    int*      bsum     = (int*)p;      p += 1024 * sizeof(int);
    int*      row_start= (int*)p;      p += (Np + 64) * sizeof(int);
    float*    dis      = (float*)p;    p += Np * sizeof(float);
    unsigned* bucketed = (unsigned*)p; p += (size_t)E * sizeof(unsigned);
    int*      csr_src  = (int*)p;      p += (size_t)E * sizeof(int);
    _Float16* bufA     = (_Float16*)p; p += Np * 64 * sizeof(_Float16);
    _Float16* bufB     = (_Float16*)p; p += Np * 64 * sizeof(_Float16);
    (void)ws_size;

    void* args[] = {
        (void*)&x, (void*)&src, (void*)&dst,
        (void*)&W1, (void*)&b1, (void*)&W2, (void*)&b2, (void*)&W3, (void*)&b3,
        (void*)&out,
        (void*)&counts_t, (void*)&offsets, (void*)&bsum, (void*)&row_start,
        (void*)&dis, (void*)&bucketed, (void*)&csr_src,
        (void*)&bufA, (void*)&bufB,
        (void*)&N, (void*)&E, (void*)&NBK
    };

    hipError_t err = hipLaunchCooperativeKernel((const void*)gcn_mega, dim3(G), dim3(256),
                                                args, 0, stream);
    // Belt-and-braces: if the runtime still rejects the grid, halve until accepted.
    int g2 = G / 2;
    while (err != hipSuccess && g2 >= 128) {
        err = hipLaunchCooperativeKernel((const void*)gcn_mega, dim3(g2), dim3(256),
                                         args, 0, stream);
        g2 /= 2;
    }
}

// Round 15
// 388.000 us; speedup vs baseline: 2.3485x; 2.3485x over previous
//
#include <hip/hip_runtime.h>

// GCN: 3 layers, dims 64->64->64->32, N=100000 nodes, E=1600000 edges.
// Round 15 = R10 (best verified, 299us) + src-sorted CSR rows.
// R14 post-mortem: cooperative mega-kernel = 1300us (grid.sync fencing across
// 8 non-coherent XCD L2s dwarfs the ~115us of dispatch gaps it removed). Reverted.
// New idea: rows in ascending-src order => the grid's parallel row walks sweep
// src space ~monotonically => gathers of the same h line cluster in time =>
// L2 hit rate up. Sort is a per-node insertion sort in bucket_build (L2-hot).
// fp16 inter-layer storage, fp32 accumulation, zero global atomics.

typedef __attribute__((ext_vector_type(8))) _Float16 half8;

static inline int cdiv(int a, int b) { return (a + b - 1) / b; }

#define ACHUNK 8192   // edges per pass-A block (256 thr x 32)
#define MAXNBK 512    // max buckets (N <= 131072)

// ---- pass A1: per-block bucket histogram -> counts_t[bucket*NBA + block]
__global__ void k_bucket_hist(const int* __restrict__ dst, int* __restrict__ counts_t,
                              int NBK, int NBA, int E) {
    __shared__ int cnt[MAXNBK];
    int t = threadIdx.x, b = blockIdx.x;
    for (int i = t; i < NBK; i += 256) cnt[i] = 0;
    __syncthreads();
    int e0 = b * ACHUNK;
#pragma unroll 8
    for (int j = 0; j < ACHUNK / 256; ++j) {
        int e = e0 + j * 256 + t;
        if (e < E) atomicAdd(&cnt[dst[e] >> 8], 1);
    }
    __syncthreads();
    for (int i = t; i < NBK; i += 256) counts_t[i * NBA + b] = cnt[i];
}

// ---- hierarchical exclusive scan: partial + (bsum-scan fused final)
#define SCAN_T 256
#define SCAN_V 4
#define SCAN_CHUNK 1024

__global__ void k_scan_partial(const int* __restrict__ a, int* __restrict__ bsum, int n) {
    __shared__ int red[SCAN_T];
    int t = threadIdx.x, b = blockIdx.x;
    int base = b * SCAN_CHUNK + t * SCAN_V;
    int s = 0;
#pragma unroll
    for (int j = 0; j < SCAN_V; ++j) { int i = base + j; if (i < n) s += a[i]; }
    red[t] = s;
    __syncthreads();
    for (int off = SCAN_T / 2; off > 0; off >>= 1) {
        if (t < off) red[t] += red[t + off];
        __syncthreads();
    }
    if (t == 0) bsum[b] = red[0];
}

// nb <= 256. Every block redundantly scans bsum in LDS, picks its base.
__global__ void k_scan_final(const int* __restrict__ a, const int* __restrict__ bsum,
                             int* __restrict__ out, int nb, int n) {
    __shared__ int sb[256];
    __shared__ int sh[SCAN_T];
    int t = threadIdx.x, bk = blockIdx.x;
    sb[t] = (t < nb) ? bsum[t] : 0;
    __syncthreads();
    for (int off = 1; off < 256; off <<= 1) {
        int u = (t >= off) ? sb[t - off] : 0;
        __syncthreads();
        sb[t] += u;
        __syncthreads();
    }
    int bbase = (bk == 0) ? 0 : sb[bk - 1];
    int base = bk * SCAN_CHUNK + t * SCAN_V;
    int v[SCAN_V];
    int s = 0;
#pragma unroll
    for (int j = 0; j < SCAN_V; ++j) {
        int i = base + j;
        v[j] = (i < n) ? a[i] : 0;
        s += v[j];
    }
    sh[t] = s;
    __syncthreads();
    for (int off = 1; off < SCAN_T; off <<= 1) {
        int u = (t >= off) ? sh[t - off] : 0;
        __syncthreads();
        sh[t] += u;
        __syncthreads();
    }
    int run = sh[t] - s + bbase;
#pragma unroll
    for (int j = 0; j < SCAN_V; ++j) {
        int i = base + j;
        if (i < n) { out[i] = run; run += v[j]; }
    }
}

// ---- pass A3: scatter edges into bucket regions via LDS cursors.
// packed word: src (24 bits) | (dst & 255) << 24.
__global__ void k_bucket_scatter(const int* __restrict__ src, const int* __restrict__ dst,
                                 const int* __restrict__ offsets, unsigned* __restrict__ bucketed,
                                 int NBK, int NBA, int E) {
    __shared__ int curs[MAXNBK];
    int t = threadIdx.x, b = blockIdx.x;
    for (int i = t; i < NBK; i += 256) curs[i] = offsets[i * NBA + b];
    __syncthreads();
    int e0 = b * ACHUNK;
#pragma unroll 8
    for (int j = 0; j < ACHUNK / 256; ++j) {
        int e = e0 + j * 256 + t;
        if (e < E) {
            int d = dst[e];
            int pos = atomicAdd(&curs[d >> 8], 1);
            bucketed[pos] = (unsigned)src[e] | ((unsigned)(d & 255) << 24);
        }
    }
}

// ---- pass B: one block per bucket. LDS hist over 256 nodes -> LDS scan ->
// emit csr_src (dst-sorted), row_start, dis; then sort each row by src.
__global__ void k_bucket_build(const unsigned* __restrict__ bucketed,
                               const int* __restrict__ offsets,
                               int* __restrict__ csr_src, int* __restrict__ row_start,
                               float* __restrict__ dis, int NBK, int NBA, int N, int E) {
    __shared__ int cnt[256];
    __shared__ int sc[256];
    int t = threadIdx.x, k = blockIdx.x;
    int base = offsets[k * NBA];
    int end = (k + 1 < NBK) ? offsets[(k + 1) * NBA] : E;
    cnt[t] = 0;
    __syncthreads();
    for (int i = base + t; i < end; i += 256)
        atomicAdd(&cnt[bucketed[i] >> 24], 1);
    __syncthreads();
    int c = cnt[t];
    sc[t] = c;
    __syncthreads();
    for (int off = 1; off < 256; off <<= 1) {
        int u = (t >= off) ? sc[t - off] : 0;
        __syncthreads();
        sc[t] += u;
        __syncthreads();
    }
    int excl = sc[t] - c;
    int node = k * 256 + t;
    if (node < N) {
        row_start[node] = base + excl;
        dis[node] = rsqrtf(1.0f + (float)c);
    }
    if (k == 0 && t == 0) row_start[N] = E;
    cnt[t] = base + excl;  // reuse as cursor
    __syncthreads();
    for (int i = base + t; i < end; i += 256) {
        unsigned w = bucketed[i];
        int pos = atomicAdd(&cnt[w >> 24], 1);
        csr_src[pos] = (int)(w & 0xFFFFFFu);
    }
    __syncthreads();
    // ---- sort this node's row ascending by src (insertion sort, L2-hot).
    // Rows avg 16, max ~45. Ascending-src rows make the grid's parallel row
    // walks sweep src space ~monotonically -> temporal clustering of gathers.
    if (node < N) {
        int st = base + excl;
        for (int i = 1; i < c; ++i) {
            int key = csr_src[st + i];
            int j = i - 1;
            while (j >= 0 && csr_src[st + j] > key) {
                csr_src[st + j + 1] = csr_src[st + j];
                --j;
            }
            csr_src[st + j + 1] = key;
        }
    }
}

// ---- fp32-input GEMM (layer 1): H = fp16((X@W) * dis[row]), 8 outs/thread
template <int K, int M>
__global__ void k_gemm_f(const float* __restrict__ X, const float* __restrict__ W,
                         const float* __restrict__ dis, _Float16* __restrict__ H, int n) {
    constexpr int TPR = M / 8;
    constexpr int ROWS = 256 / TPR;
    constexpr int KP = K + 1;
    __shared__ float Ws[K * M];
    __shared__ float Xs[ROWS * KP];
    int tid = threadIdx.x;
    for (int idx = tid; idx < K * M / 4; idx += 256)
        ((float4*)Ws)[idx] = ((const float4*)W)[idx];
    int row0 = blockIdx.x * ROWS;
    for (int idx = tid; idx < ROWS * (K / 4); idx += 256) {
        int r = idx / (K / 4), kq = idx % (K / 4);
        int row = row0 + r;
        float4 vv = (row < n) ? ((const float4*)X)[(size_t)row * (K / 4) + kq]
                              : make_float4(0.f, 0.f, 0.f, 0.f);
        Xs[r * KP + kq * 4 + 0] = vv.x;
        Xs[r * KP + kq * 4 + 1] = vv.y;
        Xs[r * KP + kq * 4 + 2] = vv.z;
        Xs[r * KP + kq * 4 + 3] = vv.w;
    }
    __syncthreads();
    int r = tid / TPR, c0 = (tid % TPR) * 8;
    int row = row0 + r;
    if (row >= n) return;
    float4 a0 = make_float4(0.f, 0.f, 0.f, 0.f);
    float4 a1 = make_float4(0.f, 0.f, 0.f, 0.f);
#pragma unroll
    for (int k = 0; k < K; ++k) {
        float xv = Xs[r * KP + k];
        float4 w0 = ((const float4*)Ws)[(k * M + c0) / 4];
        float4 w1 = ((const float4*)Ws)[(k * M + c0) / 4 + 1];
        a0.x = fmaf(xv, w0.x, a0.x);
        a0.y = fmaf(xv, w0.y, a0.y);
        a0.z = fmaf(xv, w0.z, a0.z);
        a0.w = fmaf(xv, w0.w, a0.w);
        a1.x = fmaf(xv, w1.x, a1.x);
        a1.y = fmaf(xv, w1.y, a1.y);
        a1.z = fmaf(xv, w1.z, a1.z);
        a1.w = fmaf(xv, w1.w, a1.w);
    }
    float dn = dis[row];
    half8 hv;
    hv[0] = (_Float16)(a0.x * dn);
    hv[1] = (_Float16)(a0.y * dn);
    hv[2] = (_Float16)(a0.z * dn);
    hv[3] = (_Float16)(a0.w * dn);
    hv[4] = (_Float16)(a1.x * dn);
    hv[5] = (_Float16)(a1.y * dn);
    hv[6] = (_Float16)(a1.z * dn);
    hv[7] = (_Float16)(a1.w * dn);
    ((half8*)H)[(size_t)row * (M / 8) + c0 / 8] = hv;
}

// ---- FUSED: aggregate(64) [+relu] -> LDS -> GEMM(64 x MOUT) -> h' fp16.
// 32 nodes per block (4 waves x 8 nodes, lane-per-8-features, 4-edge unroll).
template <int MOUT>
__global__ void k_fused_agg_gemm(const _Float16* __restrict__ h, const float* __restrict__ dis,
                                 const int* __restrict__ row_start, const int* __restrict__ csr_src,
                                 const float* __restrict__ bagg, const float* __restrict__ W,
                                 _Float16* __restrict__ H, int n) {
    constexpr int K = 64, KP = K + 1;
    __shared__ float Ws[K * MOUT];
    __shared__ float Xs[32 * KP];
    int tid = threadIdx.x;
    for (int idx = tid; idx < K * MOUT / 4; idx += 256)
        ((float4*)Ws)[idx] = ((const float4*)W)[idx];

    // ---- aggregate phase ----
    int wave = tid >> 6, lane = tid & 63;
    int sub = lane >> 3, fl = lane & 7;
    int node0 = blockIdx.x * 32;
    int node = node0 + wave * 8 + sub;
    if (node < n) {
        const half8* h8 = (const half8*)h;
        float acc[8];
#pragma unroll
        for (int j = 0; j < 8; ++j) acc[j] = 0.f;
        int e = row_start[node], e1 = row_start[node + 1];
        for (; e + 3 < e1; e += 4) {
            int s0 = csr_src[e], s1 = csr_src[e + 1];
            int s2 = csr_src[e + 2], s3 = csr_src[e + 3];
            half8 v0 = h8[(size_t)s0 * 8 + fl];
            half8 v1 = h8[(size_t)s1 * 8 + fl];
            half8 v2 = h8[(size_t)s2 * 8 + fl];
            half8 v3 = h8[(size_t)s3 * 8 + fl];
#pragma unroll
            for (int j = 0; j < 8; ++j)
                acc[j] += ((float)v0[j] + (float)v1[j]) + ((float)v2[j] + (float)v3[j]);
        }
        for (; e < e1; ++e) {
            int s0 = csr_src[e];
            half8 v0 = h8[(size_t)s0 * 8 + fl];
#pragma unroll
            for (int j = 0; j < 8; ++j) acc[j] += (float)v0[j];
        }
        float dn = dis[node];
        half8 hv = h8[(size_t)node * 8 + fl];
        float4 b0 = ((const float4*)bagg)[fl * 2];
        float4 b1 = ((const float4*)bagg)[fl * 2 + 1];
        int rrow = wave * 8 + sub;
        float* xp = &Xs[rrow * KP + fl * 8];
        xp[0] = fmaxf((acc[0] + (float)hv[0]) * dn + b0.x, 0.f);
        xp[1] = fmaxf((acc[1] + (float)hv[1]) * dn + b0.y, 0.f);
        xp[2] = fmaxf((acc[2] + (float)hv[2]) * dn + b0.z, 0.f);
        xp[3] = fmaxf((acc[3] + (float)hv[3]) * dn + b0.w, 0.f);
        xp[4] = fmaxf((acc[4] + (float)hv[4]) * dn + b1.x, 0.f);
        xp[5] = fmaxf((acc[5] + (float)hv[5]) * dn + b1.y, 0.f);
        xp[6] = fmaxf((acc[6] + (float)hv[6]) * dn + b1.z, 0.f);
        xp[7] = fmaxf((acc[7] + (float)hv[7]) * dn + b1.w, 0.f);
    }
    __syncthreads();

    // ---- gemm phase: 32 rows x MOUT cols, 8 cols/thread ----
    constexpr int TPR = MOUT / 8;
    int r = tid / TPR, c0 = (tid % TPR) * 8;
    int row = node0 + r;
    if (r >= 32 || row >= n) return;
    float4 a0 = make_float4(0.f, 0.f, 0.f, 0.f);
    float4 a1 = make_float4(0.f, 0.f, 0.f, 0.f);
#pragma unroll
    for (int k = 0; k < K; ++k) {
        float xv = Xs[r * KP + k];
        float4 w0 = ((const float4*)Ws)[(k * MOUT + c0) / 4];
        float4 w1 = ((const float4*)Ws)[(k * MOUT + c0) / 4 + 1];
        a0.x = fmaf(xv, w0.x, a0.x);
        a0.y = fmaf(xv, w0.y, a0.y);
        a0.z = fmaf(xv, w0.z, a0.z);
        a0.w = fmaf(xv, w0.w, a0.w);
        a1.x = fmaf(xv, w1.x, a1.x);
        a1.y = fmaf(xv, w1.y, a1.y);
        a1.z = fmaf(xv, w1.z, a1.z);
        a1.w = fmaf(xv, w1.w, a1.w);
    }
    float dn = dis[row];
    half8 hv;
    hv[0] = (_Float16)(a0.x * dn);
    hv[1] = (_Float16)(a0.y * dn);
    hv[2] = (_Float16)(a0.z * dn);
    hv[3] = (_Float16)(a0.w * dn);
    hv[4] = (_Float16)(a1.x * dn);
    hv[5] = (_Float16)(a1.y * dn);
    hv[6] = (_Float16)(a1.z * dn);
    hv[7] = (_Float16)(a1.w * dn);
    ((half8*)H)[(size_t)row * (MOUT / 8) + c0 / 8] = hv;
}

// ---- final aggregate: M=32, fp32 out, no relu. lane-per-8-features,
// LPN=4, NPW=16, 4-edge unroll.
__global__ void k_aggregate32(const _Float16* __restrict__ h, const float* __restrict__ dis,
                              const int* __restrict__ row_start, const int* __restrict__ csr_src,
                              const float* __restrict__ b, float* __restrict__ out, int n) {
    constexpr int LPN = 4, NPW = 16;
    int gtid = blockIdx.x * blockDim.x + threadIdx.x;
    int wave = gtid >> 6;
    int lane = threadIdx.x & 63;
    int sub = lane / LPN, fl = lane % LPN;
    int node = wave * NPW + sub;
    if (node >= n) return;
    const half8* h8 = (const half8*)h;
    float acc[8];
#pragma unroll
    for (int j = 0; j < 8; ++j) acc[j] = 0.f;
    int e = row_start[node], e1 = row_start[node + 1];
    for (; e + 3 < e1; e += 4) {
        int s0 = csr_src[e], s1 = csr_src[e + 1];
        int s2 = csr_src[e + 2], s3 = csr_src[e + 3];
        half8 v0 = h8[(size_t)s0 * LPN + fl];
        half8 v1 = h8[(size_t)s1 * LPN + fl];
        half8 v2 = h8[(size_t)s2 * LPN + fl];
        half8 v3 = h8[(size_t)s3 * LPN + fl];
#pragma unroll
        for (int j = 0; j < 8; ++j)
            acc[j] += ((float)v0[j] + (float)v1[j]) + ((float)v2[j] + (float)v3[j]);
    }
    for (; e < e1; ++e) {
        int s0 = csr_src[e];
        half8 v0 = h8[(size_t)s0 * LPN + fl];
#pragma unroll
        for (int j = 0; j < 8; ++j) acc[j] += (float)v0[j];
    }
    float dn = dis[node];
    half8 hv = h8[(size_t)node * LPN + fl];
    float4 b0 = ((const float4*)b)[fl * 2];
    float4 b1 = ((const float4*)b)[fl * 2 + 1];
    float4* op = (float4*)(out + ((size_t)node * LPN + fl) * 8);
    op[0] = make_float4((acc[0] + (float)hv[0]) * dn + b0.x,
                        (acc[1] + (float)hv[1]) * dn + b0.y,
                        (acc[2] + (float)hv[2]) * dn + b0.z,
                        (acc[3] + (float)hv[3]) * dn + b0.w);
    op[1] = make_float4((acc[4] + (float)hv[4]) * dn + b1.x,
                        (acc[5] + (float)hv[5]) * dn + b1.y,
                        (acc[6] + (float)hv[6]) * dn + b1.z,
                        (acc[7] + (float)hv[7]) * dn + b1.w);
}

extern "C" void kernel_launch(void* const* d_in, const int* in_sizes, int n_in,
                              void* d_out, int out_size, void* d_ws, size_t ws_size,
                              hipStream_t stream) {
    const float* x   = (const float*)d_in[0];
    const int*   ei  = (const int*)d_in[1];
    const float* W1  = (const float*)d_in[2];
    const float* b1  = (const float*)d_in[3];
    const float* W2  = (const float*)d_in[4];
    const float* b2  = (const float*)d_in[5];
    const float* W3  = (const float*)d_in[6];
    const float* b3  = (const float*)d_in[7];
    float* out = (float*)d_out;

    const int N = in_sizes[0] / 64;
    const int E = in_sizes[1] / 2;
    const int* src = ei;
    const int* dst = ei + E;

    const int NBK = cdiv(N, 256);     // 391 buckets of 256 nodes
    const int NBA = cdiv(E, ACHUNK);  // 196 pass-A blocks
    const int nmat = NBK * NBA;       // 76636 scan elements

    // workspace layout
    const size_t Np = (size_t)((N + 63) / 64) * 64;
    char* p = (char*)d_ws;
    int*      counts_t = (int*)p;      p += (size_t)nmat * sizeof(int);
    int*      offsets  = (int*)p;      p += (size_t)nmat * sizeof(int);
    int*      bsum     = (int*)p;      p += 1024 * sizeof(int);
    int*      row_start= (int*)p;      p += (Np + 64) * sizeof(int);
    float*    dis      = (float*)p;    p += Np * sizeof(float);
    unsigned* bucketed = (unsigned*)p; p += (size_t)E * sizeof(unsigned);
    int*      csr_src  = (int*)p;      p += (size_t)E * sizeof(int);
    _Float16* bufA     = (_Float16*)p; p += Np * 64 * sizeof(_Float16);
    _Float16* bufB     = (_Float16*)p; p += Np * 64 * sizeof(_Float16);
    (void)ws_size;

    const int B = 256;
    const int nb = cdiv(nmat, SCAN_CHUNK);  // 75 <= 256

    // ---- CSR build: LDS counting sort, no global atomics ----
    k_bucket_hist<<<NBA, B, 0, stream>>>(dst, counts_t, NBK, NBA, E);
    k_scan_partial<<<nb, B, 0, stream>>>(counts_t, bsum, nmat);
    k_scan_final<<<nb, B, 0, stream>>>(counts_t, bsum, offsets, nb, nmat);
    k_bucket_scatter<<<NBA, B, 0, stream>>>(src, dst, offsets, bucketed, NBK, NBA, E);
    k_bucket_build<<<NBK, B, 0, stream>>>(bucketed, offsets, csr_src, row_start, dis,
                                          NBK, NBA, N, E);

    // ---- layer 1 gemm: x(64) @ W1 -> h1 (bufA) ----
    k_gemm_f<64, 64><<<cdiv(N, 32), B, 0, stream>>>(x, W1, dis, bufA, N);
    // ---- fused: agg(h1)+relu -> gemm W2 -> h2 (bufB) ----
    k_fused_agg_gemm<64><<<cdiv(N, 32), B, 0, stream>>>(
        bufA, dis, row_start, csr_src, b1, W2, bufB, N);
    // ---- fused: agg(h2)+relu -> gemm W3 -> h3 (bufA, 32-dim) ----
    k_fused_agg_gemm<32><<<cdiv(N, 32), B, 0, stream>>>(
        bufB, dis, row_start, csr_src, b2, W3, bufA, N);
    // ---- final aggregate: agg(h3) + b3 -> out (fp32) ----
    k_aggregate32<<<cdiv(cdiv(N, 16) * 64, B), B, 0, stream>>>(
        bufA, dis, row_start, csr_src, b3, out, N);
}